// Round 5
// baseline (501.363 us; speedup 1.0000x reference)
//
#include <hip/hip_runtime.h>
#include <hip/hip_bf16.h>

// AgentEncoder: B=256, A=512, T=21, DIM=128, SC=6, NHEAD=4, HD=32
// Stage1: barrier-free per-wave pipeline (4 agents/wave), MFMA convs,
// LDS strides chosen for 16B alignment + <=2-way bank aliasing.
// Stage2: rank-1 decomposition in ego -> precomputed score/output tables.
// Float dtype (f32 vs bf16) + mask format detected at runtime.

#define BB 256
#define AAG 512
#define TT 21
#define NAG (BB * AAG)

typedef __hip_bfloat16 bf16;
typedef __attribute__((ext_vector_type(8))) short s8v;   // 8 bf16 = 4 VGPR
typedef __attribute__((ext_vector_type(4))) float f4v;   // mfma acc

__device__ int g_dtype;        // 1 = bf16 inputs, 0 = f32 inputs
__device__ int g_mask_mode;    // 0=i32, 1=u8, 2=f32, 3=bf16
__device__ __align__(16) short g_w1p[32 * 64];    // [oc][k=tap*16+ic], zero-pad
__device__ __align__(16) short g_w2p[64 * 96];    // [oc][k=tap*32+ic]
__device__ __align__(16) short g_w3p[128 * 192];  // [oc][k=tap*64+ic]
__device__ __align__(16) float g_b1[32];
__device__ __align__(16) float g_b2[64];
__device__ __align__(16) float g_b3[128];
// attention precompute
__device__ __align__(16) short g_ipwT[128 * 384]; // [e][r] transpose of in_proj_w
__device__ __align__(16) short g_opwT[128 * 128]; // [e][d] transpose of out_proj_w
__device__ __align__(16) float g_Sc[24], g_Sw[24];        // [s*4+h], pre-scaled
__device__ __align__(16) float g_P[24 * 128], g_Pw[24 * 128]; // [s*4+h][d]

template <int DT>
__device__ __forceinline__ float ldf(const void* p, long i) {
    if (DT) return __bfloat162float(((const bf16*)p)[i]);
    return ((const float*)p)[i];
}
template <int DT>
__device__ __forceinline__ void stf(void* p, long i, float v) {
    if (DT) ((bf16*)p)[i] = __float2bfloat16(v);
    else    ((float*)p)[i] = v;
}
__device__ __forceinline__ unsigned short f2bu(float x) {
    bf16 b = __float2bfloat16(x);
    union { bf16 b; unsigned short u; } cv; cv.b = b; return cv.u;
}
__device__ __forceinline__ float bu2f(unsigned short u) {
    union { unsigned int i; float f; } cv; cv.i = ((unsigned int)u) << 16; return cv.f;
}
__device__ __forceinline__ bool mask_at(const void* p, long i, int mode) {
    if (mode == 0) return ((const int*)p)[i] != 0;
    if (mode == 1) return ((const unsigned char*)p)[i] != 0;
    if (mode == 2) return ((const float*)p)[i] != 0.f;
    return (((const unsigned short*)p)[i] & 0x7fff) != 0;
}
__device__ __forceinline__ uint2 pack4(f4v acc, f4v bia, bool zero) {
    float r0 = zero ? 0.f : fmaxf(acc[0] + bia[0], 0.f);
    float r1 = zero ? 0.f : fmaxf(acc[1] + bia[1], 0.f);
    float r2 = zero ? 0.f : fmaxf(acc[2] + bia[2], 0.f);
    float r3 = zero ? 0.f : fmaxf(acc[3] + bia[3], 0.f);
    uint2 r;
    r.x = f2bu(r0) | ((unsigned int)f2bu(r1) << 16);
    r.y = f2bu(r2) | ((unsigned int)f2bu(r3) << 16);
    return r;
}

// ---------------- dtype + mask detection (1 block) ----------------
__global__ void detect_kernel(const unsigned int* __restrict__ pw,
                              const unsigned char* __restrict__ m) {
    __shared__ int cls[4];
    __shared__ int mv;
    __shared__ int good;
    int tid = threadIdx.x;
    if (tid < 4) cls[tid] = 0;
    if (tid == 0) { mv = 0; good = 0; }
    __syncthreads();
    int g = 0;
    for (int i = tid; i < 1024; i += 256) {
        unsigned int w = pw[i];
        unsigned int h0 = w & 0xffffu, h1 = w >> 16;
        unsigned int e0 = (h0 >> 7) & 0xff, e1 = (h1 >> 7) & 0xff;
        if (h0 == 0 || (e0 >= 90 && e0 <= 160)) g++;
        if (h1 == 0 || (e1 >= 90 && e1 <= 160)) g++;
    }
    atomicAdd(&good, g);
    int l0 = 0, l1 = 0, l2 = 0, l3 = 0, lm = 0;
    for (int i = tid; i < 4096; i += 256) {
        int v = m[i];
        if (v) {
            switch (i & 3) { case 0: l0 = 1; break; case 1: l1 = 1; break;
                             case 2: l2 = 1; break; default: l3 = 1; }
            if (v > lm) lm = v;
        }
    }
    if (l0) atomicOr(&cls[0], 1);
    if (l1) atomicOr(&cls[1], 1);
    if (l2) atomicOr(&cls[2], 1);
    if (l3) atomicOr(&cls[3], 1);
    atomicMax(&mv, lm);
    __syncthreads();
    if (tid == 0) {
        g_dtype = (good >= 1740) ? 1 : 0;
        int mode;
        if (!cls[1] && !cls[2] && !cls[3]) mode = 0;
        else if (!cls[0] && !cls[1])       mode = 2;
        else if (mv <= 1)                  mode = 1;
        else                               mode = 3;
        g_mask_mode = mode;
    }
}

// ---------------- weight pad/transpose/cast ----------------
template <int DT>
__global__ void prep_weights_kernel(const void* __restrict__ w1, const void* __restrict__ b1,
                                    const void* __restrict__ w2, const void* __restrict__ b2,
                                    const void* __restrict__ w3, const void* __restrict__ b3,
                                    const void* __restrict__ ipw, const void* __restrict__ opw) {
    if (g_dtype != DT) return;
    int tid = blockIdx.x * blockDim.x + threadIdx.x;
    int nt = gridDim.x * blockDim.x;
    for (int i = tid; i < 32 * 64; i += nt) {
        int oc = i >> 6, k = i & 63, tap = k >> 4, ic = k & 15;
        float v = (tap < 3 && ic < 9) ? ldf<DT>(w1, oc * 27 + ic * 3 + tap) : 0.f;
        g_w1p[i] = (short)f2bu(v);
    }
    for (int i = tid; i < 64 * 96; i += nt) {
        int oc = i / 96, k = i % 96, tap = k >> 5, ic = k & 31;
        g_w2p[i] = (short)f2bu(ldf<DT>(w2, oc * 96 + ic * 3 + tap));
    }
    for (int i = tid; i < 128 * 192; i += nt) {
        int oc = i / 192, k = i % 192, tap = k >> 6, ic = k & 63;
        g_w3p[i] = (short)f2bu(ldf<DT>(w3, oc * 192 + ic * 3 + tap));
    }
    for (int i = tid; i < 32; i += nt) g_b1[i] = ldf<DT>(b1, i);
    for (int i = tid; i < 64; i += nt) g_b2[i] = ldf<DT>(b2, i);
    for (int i = tid; i < 128; i += nt) g_b3[i] = ldf<DT>(b3, i);
    for (int i = tid; i < 384 * 128; i += nt) {
        int r = i >> 7, e = i & 127;
        g_ipwT[e * 384 + r] = (short)f2bu(ldf<DT>(ipw, i));
    }
    for (int i = tid; i < 128 * 128; i += nt) {
        int d = i >> 7, e = i & 127;
        g_opwT[e * 128 + d] = (short)f2bu(ldf<DT>(opw, i));
    }
}

// ---------------- attention precompute (1 block, 128 threads) ----------------
template <int DT>
__global__ __launch_bounds__(128) void precompute_attn_kernel(
    const void* __restrict__ se_w, const void* __restrict__ se_b,
    const void* __restrict__ pe, const void* __restrict__ query,
    const void* __restrict__ ipb) {
    if (g_dtype != DT) return;
    __shared__ float s_qu[128], s_xc[6][128], s_xw[6][128];
    __shared__ float s_q[128], s_kc[6][128], s_kw[6][128], s_vc[6][128], s_vw[6][128];
    int d = threadIdx.x;
    s_qu[d] = ldf<DT>(query, d);
#pragma unroll
    for (int s = 0; s < 6; s++) {
        s_xc[s][d] = ldf<DT>(se_b, s * 128 + d) + ldf<DT>(pe, s * 128 + d);
        s_xw[s][d] = ldf<DT>(se_w, s * 128 + d);
    }
    __syncthreads();
    float aq = ldf<DT>(ipb, d);
    float kc[6], kw[6], vc[6], vw[6];
    float bkd = ldf<DT>(ipb, 128 + d), bvd = ldf<DT>(ipb, 256 + d);
#pragma unroll
    for (int s = 0; s < 6; s++) { kc[s] = bkd; vc[s] = bvd; kw[s] = 0.f; vw[s] = 0.f; }
    for (int e = 0; e < 128; e++) {
        float wq = bu2f((unsigned short)g_ipwT[e * 384 + d]);
        float wk = bu2f((unsigned short)g_ipwT[e * 384 + 128 + d]);
        float wv = bu2f((unsigned short)g_ipwT[e * 384 + 256 + d]);
        aq = fmaf(s_qu[e], wq, aq);
#pragma unroll
        for (int s = 0; s < 6; s++) {
            float xc = s_xc[s][e], xw = s_xw[s][e];
            kc[s] = fmaf(xc, wk, kc[s]);
            kw[s] = fmaf(xw, wk, kw[s]);
            vc[s] = fmaf(xc, wv, vc[s]);
            vw[s] = fmaf(xw, wv, vw[s]);
        }
    }
    s_q[d] = aq;
#pragma unroll
    for (int s = 0; s < 6; s++) {
        s_kc[s][d] = kc[s]; s_kw[s][d] = kw[s];
        s_vc[s][d] = vc[s]; s_vw[s][d] = vw[s];
    }
    __syncthreads();
    if (d < 24) {
        int s = d >> 2, h = d & 3;
        float sc = 0.f, sw = 0.f;
        for (int j = 0; j < 32; j++) {
            sc = fmaf(s_q[h * 32 + j], s_kc[s][h * 32 + j], sc);
            sw = fmaf(s_q[h * 32 + j], s_kw[s][h * 32 + j], sw);
        }
        g_Sc[s * 4 + h] = sc * 0.17677669529663687f;
        g_Sw[s * 4 + h] = sw * 0.17677669529663687f;
    }
    // P tables: P[s][h][d] = sum_{e in head h} Wo[d][e] * Vc[s][e]
    float pc[6], pw[6];
#pragma unroll
    for (int s = 0; s < 6; s++) { pc[s] = 0.f; pw[s] = 0.f; }
    for (int e = 0; e < 128; e++) {
        float wo = bu2f((unsigned short)g_opwT[e * 128 + d]);
#pragma unroll
        for (int s = 0; s < 6; s++) {
            pc[s] = fmaf(wo, s_vc[s][e], pc[s]);
            pw[s] = fmaf(wo, s_vw[s][e], pw[s]);
        }
        if ((e & 31) == 31) {
            int h = e >> 5;
#pragma unroll
            for (int s = 0; s < 6; s++) {
                g_P[(s * 4 + h) * 128 + d] = pc[s];
                g_Pw[(s * 4 + h) * 128 + d] = pw[s];
                pc[s] = 0.f; pw[s] = 0.f;
            }
        }
    }
}

// ---------------- stage 1: barrier-free per-wave pipeline ----------------
// Per-wave LDS slice (shorts): feat @0 (2336 = 4ag x 584; row stride 24),
// h1 @2336 (1952 = 4 x 488; row 40), h2 @4288 (2080 = 4 x 520; row 72),
// c3 overlays feat (4 x 408; row 136). Wave stride 6368 shorts + 128 pad.
#define F_RS 24
#define F_AS 584
#define H1_RS 40
#define H1_AS 488
#define H2_RS 72
#define H2_AS 520
#define C3_RS 136
#define C3_AS 408
#define WAVE_STRIDE 6368

#define MFMA16(a, b, c) __builtin_amdgcn_mfma_f32_16x16x32_bf16((a), (b), (c), 0, 0, 0)

template <int DT>
__global__ __launch_bounds__(256) void stage1_kernel(
    const void* __restrict__ pos, const void* __restrict__ heading,
    const void* __restrict__ vel, const void* __restrict__ shp,
    const void* __restrict__ vmask, const int* __restrict__ category,
    const void* __restrict__ type_emb, void* __restrict__ out) {
    if (g_dtype != DT) return;
    __shared__ __align__(16) short sm[4 * WAVE_STRIDE + 128];
    __shared__ int sval[16];

    const int tid = threadIdx.x;
    const int wave = tid >> 6, lane = tid & 63;
    const int col = lane & 15, quad = lane >> 4;
    const int mode = g_mask_mode;
    short* feat = sm + wave * WAVE_STRIDE;
    short* h1 = feat + 2336;
    short* h2 = feat + 4288;
    short* c3 = feat;                 // overlay: feat dead before conv3 writes
    int* wv = sval + wave * 4;
    const long agent0 = (long)blockIdx.x * 16 + wave * 4;

    if (lane < 4) wv[lane] = 0;

    // ---- feature build: 96 tasks = 4 agents x rows t=0..23 ----
    for (int it = 0; it < 2; it++) {
        int idx = it * 64 + lane;
        if (idx < 96) {
            int ag = idx / 24, t = idx - ag * 24;
            short* row = feat + ag * F_AS + t * F_RS;
            long base = (agent0 + ag) * TT + t;
            if (t <= 19) {
                bool vmt = mask_at(vmask, base, mode);
                if (vmt) atomicOr(&wv[ag], 1);
                bool m2 = vmt && mask_at(vmask, base + 1, mode);
                float px0 = ldf<DT>(pos, base * 2),     py0 = ldf<DT>(pos, base * 2 + 1);
                float px1 = ldf<DT>(pos, base * 2 + 2), py1 = ldf<DT>(pos, base * 2 + 3);
                float vx0 = ldf<DT>(vel, base * 2),     vy0 = ldf<DT>(vel, base * 2 + 1);
                float vx1 = ldf<DT>(vel, base * 2 + 2), vy1 = ldf<DT>(vel, base * 2 + 3);
                float hh0 = ldf<DT>(heading, base), hh1 = ldf<DT>(heading, base + 1);
                float sx = ldf<DT>(shp, base * 2 + 2), sy = ldf<DT>(shp, base * 2 + 3);
                float dh = m2 ? (hh1 - hh0) : 0.f;   // masked: cos=1, sin=0 (ref)
                float sn = sinf(dh), cn = cosf(dh);
                unsigned int p0 = f2bu(m2 ? px1 - px0 : 0.f) | ((unsigned int)f2bu(m2 ? py1 - py0 : 0.f) << 16);
                unsigned int p1 = f2bu(m2 ? vx1 - vx0 : 0.f) | ((unsigned int)f2bu(m2 ? vy1 - vy0 : 0.f) << 16);
                unsigned int p2 = f2bu(cn) | ((unsigned int)f2bu(sn) << 16);
                unsigned int p3 = f2bu(sx) | ((unsigned int)f2bu(sy) << 16);
                unsigned int p4 = (unsigned int)f2bu(m2 ? 1.f : 0.f);
                *(uint4*)row = make_uint4(p0, p1, p2, p3);
                *(uint4*)(row + 8) = make_uint4(p4, 0, 0, 0);
            } else if (t <= 21) {
                *(uint4*)row = make_uint4(0, 0, 0, 0);
                *(uint4*)(row + 8) = make_uint4(0, 0, 0, 0);
                if (t == 20 && mask_at(vmask, base, mode)) atomicOr(&wv[ag], 1);
            }
            // t=22,23: garbage rows, only ever read by discarded lanes
        }
    }
    // zero h2 row 0 (SAME left pad for conv3)
    if (lane < 32) {
        int ag = lane >> 3, j = lane & 7;
        *(uint4*)(h2 + ag * H2_AS + j * 8) = make_uint4(0, 0, 0, 0);
    }

    // ---- conv1: M=32, K=64 (taps 0..2 + zero tap3), N=48 (4ag x 12 pos) ----
    {
        int rofs = (quad >> 1) * F_RS + (quad & 1) * 8;
#pragma unroll
        for (int mt = 0; mt < 2; mt++) {
            int oc = mt * 16 + col;
            s8v a0 = *(const s8v*)(g_w1p + oc * 64 + quad * 8);
            s8v a1 = *(const s8v*)(g_w1p + oc * 64 + 32 + quad * 8);
            f4v bia = *(const f4v*)(g_b1 + mt * 16 + quad * 4);
#pragma unroll
            for (int nt = 0; nt < 3; nt++) {
                int n = nt * 16 + col;
                int ag = (n * 171) >> 11;   // n/12 for n<48
                int p = n - ag * 12;
                const short* bb = feat + ag * F_AS + 2 * p * F_RS + rofs;
                s8v b0 = *(const s8v*)(bb);
                s8v b1 = *(const s8v*)(bb + 2 * F_RS);
                f4v acc = {0.f, 0.f, 0.f, 0.f};
                acc = MFMA16(a0, b0, acc);
                acc = MFMA16(a1, b1, acc);
                // p=10 is h1's zero pad row; p=11 writes never-read row 11
                *(uint2*)(h1 + ag * H1_AS + p * H1_RS + mt * 16 + quad * 4) =
                    pack4(acc, bia, p == 10);
            }
        }
    }

    // ---- conv2: M=64, K=96, N=32 (4ag x 8 pos; real p<=4) ----
    {
#pragma unroll
        for (int mt = 0; mt < 4; mt++) {
            int oc = mt * 16 + col;
            s8v a0 = *(const s8v*)(g_w2p + oc * 96 + quad * 8);
            s8v a1 = *(const s8v*)(g_w2p + oc * 96 + 32 + quad * 8);
            s8v a2 = *(const s8v*)(g_w2p + oc * 96 + 64 + quad * 8);
            f4v bia = *(const f4v*)(g_b2 + mt * 16 + quad * 4);
#pragma unroll
            for (int nt = 0; nt < 2; nt++) {
                int n = nt * 16 + col;
                int ag = n >> 3, p = n & 7;
                const short* hb = h1 + ag * H1_AS + 2 * p * H1_RS + quad * 8;
                f4v acc = {0.f, 0.f, 0.f, 0.f};
                acc = MFMA16(a0, *(const s8v*)(hb), acc);
                acc = MFMA16(a1, *(const s8v*)(hb + H1_RS), acc);
                acc = MFMA16(a2, *(const s8v*)(hb + 2 * H1_RS), acc);
                if (p < 6) {   // p=5 -> zero pad row 6; p>=6 discarded
                    *(uint2*)(h2 + ag * H2_AS + (p + 1) * H2_RS + mt * 16 + quad * 4) =
                        pack4(acc, bia, p == 5);
                }
            }
        }
    }

    // ---- conv3: M=128, K=192, N=16 (4ag x 4 pos; real p<=2) ----
    {
        int ag = col >> 2, p = col & 3;
        const short* hb = h2 + ag * H2_AS + 2 * p * H2_RS;
#pragma unroll
        for (int mt = 0; mt < 8; mt++) {
            int oc = mt * 16 + col;
            s8v a[6];
#pragma unroll
            for (int ks = 0; ks < 6; ks++)
                a[ks] = *(const s8v*)(g_w3p + oc * 192 + ks * 32 + quad * 8);
            f4v bia = *(const f4v*)(g_b3 + mt * 16 + quad * 4);
            f4v acc = {0.f, 0.f, 0.f, 0.f};
#pragma unroll
            for (int ks = 0; ks < 6; ks++) {
                int kg = ks * 32 + quad * 8;
                int tap = kg >> 6, ic = kg & 63;
                acc = MFMA16(a[ks], *(const s8v*)(hb + tap * H2_RS + ic), acc);
            }
            if (p < 3) {
                *(uint2*)(c3 + ag * C3_AS + p * C3_RS + mt * 16 + quad * 4) =
                    pack4(acc, bia, false);
            }
        }
    }

    // ---- epilogue: mean over 3 positions, valid mask, + type_emb ----
    {
        int ag = lane >> 4, j = lane & 15, ocg = j * 8;
        const short* cb = c3 + ag * C3_AS + j * 8;
        s8v x0 = *(const s8v*)(cb);
        s8v x1 = *(const s8v*)(cb + C3_RS);
        s8v x2 = *(const s8v*)(cb + 2 * C3_RS);
        int valid = wv[ag];
        long agent = agent0 + ag;
        int cat = category[agent];
        float r[8];
#pragma unroll
        for (int jj = 0; jj < 8; jj++) {
            float m = (bu2f((unsigned short)x0[jj]) + bu2f((unsigned short)x1[jj]) +
                       bu2f((unsigned short)x2[jj])) * (1.f / 3.f);
            r[jj] = valid ? m : 0.f;
        }
        if (DT) {
            const short* tep = (const short*)type_emb + cat * 128 + ocg;
            s8v te = *(const s8v*)tep;
            unsigned int o[4];
#pragma unroll
            for (int q = 0; q < 4; q++) {
                o[q] = f2bu(r[2 * q] + bu2f((unsigned short)te[2 * q])) |
                       ((unsigned int)f2bu(r[2 * q + 1] + bu2f((unsigned short)te[2 * q + 1])) << 16);
            }
            *(uint4*)((short*)out + agent * 128 + ocg) = make_uint4(o[0], o[1], o[2], o[3]);
        } else {
            const float* tep = (const float*)type_emb + cat * 128 + ocg;
            float4 t0 = *(const float4*)tep;
            float4 t1 = *(const float4*)(tep + 4);
            float4 o0 = make_float4(r[0] + t0.x, r[1] + t0.y, r[2] + t0.z, r[3] + t0.w);
            float4 o1 = make_float4(r[4] + t1.x, r[5] + t1.y, r[6] + t1.z, r[7] + t1.w);
            float* op = (float*)out + agent * 128 + ocg;
            *(float4*)op = o0;
            *(float4*)(op + 4) = o1;
        }
    }
}

// ---------------- stage 2: table-based ego attention, overwrites row a=0 ----------------
template <int DT>
__global__ __launch_bounds__(128) void stage2_kernel(
    const void* __restrict__ cs, const int* __restrict__ category,
    const void* __restrict__ opb, const void* __restrict__ type_emb,
    void* __restrict__ out) {
    if (g_dtype != DT) return;
    int b = blockIdx.x, d = threadIdx.x;
    float ego[6];
#pragma unroll
    for (int s = 0; s < 6; s++) ego[s] = ldf<DT>(cs, b * 6 + s);
    float a[4][6];
#pragma unroll
    for (int h = 0; h < 4; h++) {
        float mx = -1e30f;
#pragma unroll
        for (int s = 0; s < 6; s++) {
            float t = fmaf(ego[s], g_Sw[s * 4 + h], g_Sc[s * 4 + h]);
            a[h][s] = t;
            mx = fmaxf(mx, t);
        }
        float sum = 0.f;
#pragma unroll
        for (int s = 0; s < 6; s++) { a[h][s] = expf(a[h][s] - mx); sum += a[h][s]; }
        float inv = 1.f / sum;
#pragma unroll
        for (int s = 0; s < 6; s++) a[h][s] *= inv;
    }
    int cat = category[(long)b * AAG];
    float acc = ldf<DT>(opb, d) + ldf<DT>(type_emb, cat * 128 + d);
#pragma unroll
    for (int s = 0; s < 6; s++)
#pragma unroll
        for (int h = 0; h < 4; h++) {
            float pv = fmaf(ego[s], g_Pw[(s * 4 + h) * 128 + d], g_P[(s * 4 + h) * 128 + d]);
            acc = fmaf(a[h][s], pv, acc);
        }
    stf<DT>(out, (long)b * AAG * 128 + d, acc);
}

extern "C" void kernel_launch(void* const* d_in, const int* in_sizes, int n_in,
                              void* d_out, int out_size, void* d_ws, size_t ws_size,
                              hipStream_t stream) {
    const void* position      = d_in[0];
    const void* heading       = d_in[1];
    const void* velocity      = d_in[2];
    const void* shape         = d_in[3];
    const void* current_state = d_in[4];
    const int*  category      = (const int*)d_in[5];
    const void* valid_mask    = d_in[6];
    const void* conv1_w = d_in[7];
    const void* conv1_b = d_in[8];
    const void* conv2_w = d_in[9];
    const void* conv2_b = d_in[10];
    const void* conv3_w = d_in[11];
    const void* conv3_b = d_in[12];
    const void* se_w    = d_in[13];
    const void* se_b    = d_in[14];
    const void* pos_embed = d_in[15];
    const void* query     = d_in[16];
    const void* in_proj_w = d_in[17];
    const void* in_proj_b = d_in[18];
    const void* out_proj_w = d_in[19];
    const void* out_proj_b = d_in[20];
    const void* type_emb   = d_in[21];

    hipLaunchKernelGGL(detect_kernel, dim3(1), dim3(256), 0, stream,
                       (const unsigned int*)position, (const unsigned char*)valid_mask);

    hipLaunchKernelGGL(prep_weights_kernel<0>, dim3(64), dim3(256), 0, stream,
                       conv1_w, conv1_b, conv2_w, conv2_b, conv3_w, conv3_b,
                       in_proj_w, out_proj_w);
    hipLaunchKernelGGL(prep_weights_kernel<1>, dim3(64), dim3(256), 0, stream,
                       conv1_w, conv1_b, conv2_w, conv2_b, conv3_w, conv3_b,
                       in_proj_w, out_proj_w);

    hipLaunchKernelGGL(precompute_attn_kernel<0>, dim3(1), dim3(128), 0, stream,
                       se_w, se_b, pos_embed, query, in_proj_b);
    hipLaunchKernelGGL(precompute_attn_kernel<1>, dim3(1), dim3(128), 0, stream,
                       se_w, se_b, pos_embed, query, in_proj_b);

    hipLaunchKernelGGL(stage1_kernel<0>, dim3(NAG / 16), dim3(256), 0, stream,
                       position, heading, velocity, shape, valid_mask, category, type_emb, d_out);
    hipLaunchKernelGGL(stage1_kernel<1>, dim3(NAG / 16), dim3(256), 0, stream,
                       position, heading, velocity, shape, valid_mask, category, type_emb, d_out);

    hipLaunchKernelGGL(stage2_kernel<0>, dim3(BB), dim3(128), 0, stream,
                       current_state, category, out_proj_b, type_emb, d_out);
    hipLaunchKernelGGL(stage2_kernel<1>, dim3(BB), dim3(128), 0, stream,
                       current_state, category, out_proj_b, type_emb, d_out);
}